// Round 14
// baseline (269772.437 us; speedup 1.0000x reference)
//
#include <hip/hip_runtime.h>
#include <math.h>

#define DEV_INLINE __device__ __forceinline__

static constexpr int Bn = 64;     // batch
static constexpr int Tn = 512;    // time
static constexpr int En = 512;    // embed
static constexpr int Hn = 1024;   // hidden
static constexpr int Cn = 256;    // classes
static constexpr int Gn = 4 * Hn; // 4096 gates

typedef float v4f __attribute__((ext_vector_type(4)));
typedef unsigned int v4u __attribute__((ext_vector_type(4)));
typedef _Float16 v8h __attribute__((ext_vector_type(8)));
typedef unsigned long long ull;

DEV_INLINE float sigmoidf_(float v) { return 1.f / (1.f + __expf(-v)); }

// ---------------------------------------------------------------------------
// fp32 tiled GEMM:  C[M,N] = A[M,K] * B[N,K]^T + bias1[n] (+bias2[n])
// ---------------------------------------------------------------------------
__global__ __launch_bounds__(256) void gemm_tt(
    const float* __restrict__ A, const float* __restrict__ Bm,
    const float* __restrict__ bias1, const float* __restrict__ bias2,
    float* __restrict__ Cm, int M, int N, int K)
{
  constexpr int KC = 32;
  __shared__ float As[KC][68];
  __shared__ float Bs[KC][68];
  const int tid = threadIdx.x;
  const int tx = tid & 15, ty = tid >> 4;
  const int m0 = blockIdx.x * 64, n0 = blockIdx.y * 64;

  float acc[4][4] = {};

  for (int k0 = 0; k0 < K; k0 += KC) {
    __syncthreads();
    #pragma unroll
    for (int j = 0; j < 2; ++j) {
      int f = tid + j * 256;
      int row = f >> 3;
      int c4 = f & 7;
      float4 va = *reinterpret_cast<const float4*>(&A[(size_t)(m0 + row) * K + k0 + c4 * 4]);
      As[c4 * 4 + 0][row] = va.x; As[c4 * 4 + 1][row] = va.y;
      As[c4 * 4 + 2][row] = va.z; As[c4 * 4 + 3][row] = va.w;
      float4 vb = *reinterpret_cast<const float4*>(&Bm[(size_t)(n0 + row) * K + k0 + c4 * 4]);
      Bs[c4 * 4 + 0][row] = vb.x; Bs[c4 * 4 + 1][row] = vb.y;
      Bs[c4 * 4 + 2][row] = vb.z; Bs[c4 * 4 + 3][row] = vb.w;
    }
    __syncthreads();
    #pragma unroll
    for (int k = 0; k < KC; ++k) {
      float4 a4 = *reinterpret_cast<const float4*>(&As[k][ty * 4]);
      float4 b4 = *reinterpret_cast<const float4*>(&Bs[k][tx * 4]);
      float ar[4] = {a4.x, a4.y, a4.z, a4.w};
      float br[4] = {b4.x, b4.y, b4.z, b4.w};
      #pragma unroll
      for (int i = 0; i < 4; ++i)
        #pragma unroll
        for (int j = 0; j < 4; ++j)
          acc[i][j] += ar[i] * br[j];
    }
  }

  #pragma unroll
  for (int j = 0; j < 4; ++j) {
    int n = n0 + tx * 4 + j;
    float bb = bias1[n];
    if (bias2) bb += bias2[n];
    #pragma unroll
    for (int i = 0; i < 4; ++i)
      Cm[(size_t)(m0 + ty * 4 + i) * N + n] = acc[i][j] + bb;
  }
}

// ---------------------------------------------------------------------------
__global__ __launch_bounds__(256) void cvt_fcw(
    const float* __restrict__ fcW, _Float16* __restrict__ fcW16)
{
  const int idx = (blockIdx.x * 256 + threadIdx.x) * 8;
  float4 f0 = *(const float4*)(fcW + idx);
  float4 f1 = *(const float4*)(fcW + idx + 4);
  v8h h8;
  h8[0] = (_Float16)f0.x; h8[1] = (_Float16)f0.y;
  h8[2] = (_Float16)f0.z; h8[3] = (_Float16)f0.w;
  h8[4] = (_Float16)f1.x; h8[5] = (_Float16)f1.y;
  h8[6] = (_Float16)f1.z; h8[7] = (_Float16)f1.w;
  *(v8h*)(fcW16 + idx) = h8;
}

// ---------------------------------------------------------------------------
// per-call generation bump (gen cell lives OUTSIDE the memset region)
// ---------------------------------------------------------------------------
__global__ void gen_bump(unsigned* g) {
  if (threadIdx.x == 0)
    __hip_atomic_fetch_add(g, 1u, __ATOMIC_RELAXED, __HIP_MEMORY_SCOPE_AGENT);
}

// ---------------------------------------------------------------------------
// Fused persistent kernel, 256 blocks x 512 threads.
// LSTM blocks: (bid&7)<4 -> bg=bid&3, hg=bid>>3. Under round-robin dispatch
// (bid%8 -> XCD) each bg lands WHOLLY on one XCD; nothing depends on it.
// FC blocks: (bid&7)>=4 -> fid=(bid>>3)*4+(bid&3); R12 path, unchanged.
//
// Exchange, dual-published by producers each step:
//  (1) FAST: 16B tagged records (8B h payload | 0 | tag<<16) to hxL with
//      sc0 (L1-bypass -> producer's L2). tag=((gen&63)<<9|t)+1; gen bumped
//      per call -> stale lines from prior replays can never tag-match.
//      Fire-and-forget (16B atomicity: tag visible => payload visible).
//  (2) SLOW (R12, verified): sc0 sc1 h rows -> vmcnt drain -> sc1 flag.
// Consumers: t==1 stages via SLOW path (always correct), then probes its
// own record line (sc0, 16 bounded iters; flag-seen => records drained, so
// same-XCD lines MUST be readable). All-threads-pass => mode=LOCAL else
// DEVICE, fixed for t>=2 (placement is static within a launch).
// t>=2 LOCAL: poll-own-records = staging (local L2 RT), scatter, MFMA —
// no flag wait, no producer drain on the critical path. Bounded 2^20 with
// block-uniform flip to DEVICE => deadlock impossible by construction.
// ---------------------------------------------------------------------------
__global__ __launch_bounds__(512, 2) void lstm_fused(
    const int* __restrict__ x,          // [B, T]
    const float* __restrict__ Whh,      // [4H, H] fp32
    const float* __restrict__ proj,     // [C, 4H] incl. both biases
    _Float16* __restrict__ hs16,        // [T, B, H] fp16 rows (FC + fallback)
    int* __restrict__ flags,            // [Tn][4][32] dwords (128B lines)
    char* __restrict__ hxL,             // [2][4][32][128] x 16B tagged records
    unsigned* __restrict__ genc,        // generation cell (not memset)
    const _Float16* __restrict__ fcW16, // [256][1024] fp16
    const float* __restrict__ fcb,      // [256]
    float* __restrict__ out)            // [64][512][256] fp32
{
  __shared__ __align__(16) char hT[32768];   // staged h tile, fragment-linear
  __shared__ _Float16 hstage[16 * 40];       // stride 40: bank spread
  __shared__ int modeS, failS;
  __shared__ unsigned genS;

  const int tid = threadIdx.x;
  const int bid = blockIdx.x;

  const int w = tid >> 6, l = tid & 63;
  const int mrow = l & 15;
  const int kseg = l >> 4;

  // staging source offset for the SLOW (row) path
  const int srcoff = (tid & 15) * 2048 + ((tid >> 4) & 3) * 16 + (tid >> 6) * 64;

  if (tid == 0) {
    modeS = 0; failS = 0;
    genS = __hip_atomic_load(genc, __ATOMIC_RELAXED, __HIP_MEMORY_SCOPE_AGENT);
  }
  __syncthreads();
  const unsigned gen6 = (genS & 63u) << 9;

  if ((bid & 7) < 4) {
    // =========================== LSTM path ===============================
    const int bg = bid & 3, hg = bid >> 3;
    const int b0 = bg * 16;

    // ---- W preload: A-row m=l&15 -> (gate=m&3, hcolLocal=w*4+(m>>2))
    v8h wv[32];
    {
      const float* wr = Whh
        + (size_t)((mrow & 3) * Hn + hg * 32 + w * 4 + (mrow >> 2)) * Hn
        + kseg * 8;
      #pragma unroll
      for (int kk = 0; kk < 32; ++kk) {
        const float* p = wr + kk * 32;
        float4 f0 = *(const float4*)p, f1 = *(const float4*)(p + 4);
        v8h h8;
        h8[0] = (_Float16)f0.x; h8[1] = (_Float16)f0.y;
        h8[2] = (_Float16)f0.z; h8[3] = (_Float16)f0.w;
        h8[4] = (_Float16)f1.x; h8[5] = (_Float16)f1.y;
        h8[6] = (_Float16)f1.z; h8[7] = (_Float16)f1.w;
        wv[kk] = h8;
      }
    }

    const int eb = mrow;            // elementwise: batch l&15
    const int ehc = w * 4 + kseg;   // hcol local
    const int* xp = x + (size_t)(b0 + eb) * Tn;
    float cst = 0.f;

    // record-line addresses (consumer: producer p=tid>>4, batch=tid&15)
    const int csrc  = (tid >> 4) * 2048 + (tid & 15) * 128;
    const int dbase = (tid >> 4) * 1024 + (tid & 15) * 16;

    for (int t = 0; t < Tn; ++t) {
      const int cls = xp[t];
      const float* pb = proj + (size_t)cls * Gn + hg * 32 + ehc;
      float p0 = pb[0], p1 = pb[Hn], p2 = pb[2 * Hn], p3 = pb[3 * Hn];

      v4f acc0 = {0.f, 0.f, 0.f, 0.f};
      v4f acc1 = {0.f, 0.f, 0.f, 0.f};

      if (t > 0) {
        const int doLocal = (t > 1) ? modeS : 0;
        int staged = 0;

        if (doLocal) {
          // ---- FAST: poll own 128B record line until all 8 tags match
          const unsigned tagv = (gen6 | (unsigned)(t - 1)) + 1u;
          const char* pp = hxL + (size_t)((t - 1) & 1) * 262144
                         + bg * 65536 + csrc;
          v4u r0, r1, r2, r3, r4, r5, r6, r7;
          int ok = 0;
          for (int it = 0; it < (1 << 20); ++it) {
            asm volatile(
              "global_load_dwordx4 %0, %8, off sc0\n\t"
              "global_load_dwordx4 %1, %8, off offset:16 sc0\n\t"
              "global_load_dwordx4 %2, %8, off offset:32 sc0\n\t"
              "global_load_dwordx4 %3, %8, off offset:48 sc0\n\t"
              "global_load_dwordx4 %4, %8, off offset:64 sc0\n\t"
              "global_load_dwordx4 %5, %8, off offset:80 sc0\n\t"
              "global_load_dwordx4 %6, %8, off offset:96 sc0\n\t"
              "global_load_dwordx4 %7, %8, off offset:112 sc0\n\t"
              "s_waitcnt vmcnt(0)"
              : "=&v"(r0), "=&v"(r1), "=&v"(r2), "=&v"(r3),
                "=&v"(r4), "=&v"(r5), "=&v"(r6), "=&v"(r7)
              : "v"(pp) : "memory");
            unsigned m = ((r0.w >> 16) ^ tagv) | ((r1.w >> 16) ^ tagv)
                       | ((r2.w >> 16) ^ tagv) | ((r3.w >> 16) ^ tagv)
                       | ((r4.w >> 16) ^ tagv) | ((r5.w >> 16) ^ tagv)
                       | ((r6.w >> 16) ^ tagv) | ((r7.w >> 16) ^ tagv);
            if (m == 0u) { ok = 1; break; }
          }
          if (!ok) failS = 1;
          __syncthreads();
          if (!failS) {
            v4u rr[8] = {r0, r1, r2, r3, r4, r5, r6, r7};
            #pragma unroll
            for (int i = 0; i < 8; ++i)
              *(ull*)(hT + dbase + (i >> 1) * 256 + (i & 1) * 8)
                = ((ull)rr[i].y << 32) | (ull)rr[i].x;
            staged = 1;
          } else if (tid == 0) {
            modeS = 0;                       // permanent flip to DEVICE
          }
          __syncthreads();
          if (tid == 0) failS = 0;           // next write is next step (ordered)
        }

        if (!staged) {
          // ---- SLOW (R12-verified): flag poll + row stage
          if (tid < 32) {
            const int* fp = flags + ((size_t)(t - 1) * 4 + bg) * 32 + tid;
            int v;
            do {
              asm volatile(
                "global_load_dword %0, %1, off sc0 sc1\n\t"
                "s_waitcnt vmcnt(0)"
                : "=v"(v) : "v"(fp) : "memory");
            } while (v == 0);
          }
          __syncthreads();
          const char* s0 = (const char*)(hs16 + ((size_t)(t - 1) * Bn + b0) * Hn)
                         + srcoff;
          v4f q0, q1, q2, q3;
          asm volatile(
            "global_load_dwordx4 %0, %4, off sc0 sc1\n\t"
            "global_load_dwordx4 %1, %5, off sc0 sc1\n\t"
            "global_load_dwordx4 %2, %6, off sc0 sc1\n\t"
            "global_load_dwordx4 %3, %7, off sc0 sc1\n\t"
            "s_waitcnt vmcnt(0)"
            : "=&v"(q0), "=&v"(q1), "=&v"(q2), "=&v"(q3)
            : "v"(s0), "v"(s0 + 512), "v"(s0 + 1024), "v"(s0 + 1536)
            : "memory");
          *(v4f*)(hT + tid * 16 +     0) = q0;
          *(v4f*)(hT + tid * 16 +  8192) = q1;
          *(v4f*)(hT + tid * 16 + 16384) = q2;
          *(v4f*)(hT + tid * 16 + 24576) = q3;

          if (t == 1) {
            // ---- probe: flag-seen => records drained; readable iff local
            const unsigned tagv = (gen6 | 0u) + 1u;
            const char* pp = hxL + bg * 65536 + csrc;   // slot 0
            int ok = 0;
            for (int it = 0; it < 16; ++it) {
              v4u r0p, r7p;
              asm volatile(
                "global_load_dwordx4 %0, %2, off sc0\n\t"
                "global_load_dwordx4 %1, %2, off offset:112 sc0\n\t"
                "s_waitcnt vmcnt(0)"
                : "=&v"(r0p), "=&v"(r7p) : "v"(pp) : "memory");
              if ((((r0p.w >> 16) ^ tagv) | ((r7p.w >> 16) ^ tagv)) == 0u) {
                ok = 1; break;
              }
            }
            if (!ok) failS = 1;
            __syncthreads();
            if (tid == 0) { modeS = failS ? 0 : 1; failS = 0; }
          }
        }
        __syncthreads();

        #pragma unroll
        for (int kk = 0; kk < 32; kk += 2) {
          v8h a0 = *(const v8h*)(hT + kk * 1024 + l * 16);
          v8h a1 = *(const v8h*)(hT + (kk + 1) * 1024 + l * 16);
          acc0 = __builtin_amdgcn_mfma_f32_16x16x32_f16(wv[kk], a0, acc0, 0, 0, 0);
          acc1 = __builtin_amdgcn_mfma_f32_16x16x32_f16(wv[kk + 1], a1, acc1, 0, 0, 0);
        }
      }

      // gates in-register: acc[r] = gate r of (eb, ehc)
      {
        float g0 = acc0[0] + acc1[0] + p0;
        float g1 = acc0[1] + acc1[1] + p1;
        float g2 = acc0[2] + acc1[2] + p2;
        float g3 = acc0[3] + acc1[3] + p3;
        float ig = sigmoidf_(g0), fg = sigmoidf_(g1);
        float gg = tanhf(g2),     og = sigmoidf_(g3);
        cst = fg * cst + ig * gg;
        hstage[eb * 40 + ehc] = (_Float16)(og * tanhf(cst));
      }
      __syncthreads();

      // ---- publish: FAST records first (fire-and-forget), then SLOW rows
      if (tid < 128) {
        const int batch = tid >> 3, cg = tid & 7;
        ull d = *(const ull*)(hstage + batch * 40 + cg * 4);
        v4u val;
        val.x = (unsigned)d;
        val.y = (unsigned)(d >> 32);
        val.z = 0u;
        val.w = ((gen6 | (unsigned)t) + 1u) << 16;
        char* dst = hxL + (size_t)(t & 1) * 262144 + bg * 65536
                  + hg * 2048 + tid * 16;
        asm volatile("global_store_dwordx4 %0, %1, off sc0"
                     :: "v"(dst), "v"(val) : "memory");
      }
      if (tid < 64) {
        const int b = tid >> 2, part = tid & 3;
        v4f v = *(const v4f*)(hstage + b * 40 + part * 8);
        _Float16* dp = hs16 + ((size_t)t * Bn + b0 + b) * Hn + hg * 32 + part * 8;
        asm volatile(
          "global_store_dwordx4 %0, %1, off sc0 sc1\n\t"
          "s_waitcnt vmcnt(0)"
          :: "v"(dp), "v"(v) : "memory");
        if (tid == 0) {
          int one = 1;
          int* fq = flags + ((size_t)t * 4 + bg) * 32 + hg;
          asm volatile("global_store_dword %0, %1, off sc0 sc1"
                       :: "v"(fq), "v"(one) : "memory");
        }
      }
      __syncthreads();   // hstage/hT reuse next step
    }
  } else {
    // ============================ FC path ================================
    const int fid = (bid >> 3) * 4 + (bid & 3);

    for (int j = 0; j < 16; ++j) {
      const int unit = j * 128 + fid;          // 0..2047
      const int t = unit >> 2, bgf = unit & 3;
      const int b0f = bgf * 16;

      if (tid < 32) {
        const int* fp = flags + ((size_t)t * 4 + bgf) * 32 + tid;
        int v;
        for (;;) {
          asm volatile(
            "global_load_dword %0, %1, off sc0 sc1\n\t"
            "s_waitcnt vmcnt(0)"
            : "=v"(v) : "v"(fp) : "memory");
          if (v != 0) break;
          __builtin_amdgcn_s_sleep(64);
        }
      }
      __syncthreads();

      {
        const char* s0 = (const char*)(hs16 + ((size_t)t * Bn + b0f) * Hn)
                       + srcoff;
        v4f r0, r1, r2, r3;
        asm volatile(
          "global_load_dwordx4 %0, %4, off sc0 sc1\n\t"
          "global_load_dwordx4 %1, %5, off sc0 sc1\n\t"
          "global_load_dwordx4 %2, %6, off sc0 sc1\n\t"
          "global_load_dwordx4 %3, %7, off sc0 sc1\n\t"
          "s_waitcnt vmcnt(0)"
          : "=&v"(r0), "=&v"(r1), "=&v"(r2), "=&v"(r3)
          : "v"(s0), "v"(s0 + 512), "v"(s0 + 1024), "v"(s0 + 1536)
          : "memory");
        *(v4f*)(hT + tid * 16 +     0) = r0;
        *(v4f*)(hT + tid * 16 +  8192) = r1;
        *(v4f*)(hT + tid * 16 + 16384) = r2;
        *(v4f*)(hT + tid * 16 + 24576) = r3;
      }
      __syncthreads();

      #pragma unroll
      for (int nt = 0; nt < 2; ++nt) {
        const int clsbase = w * 32 + nt * 16;
        v4f acc = {0.f, 0.f, 0.f, 0.f};
        const _Float16* ab = fcW16 + (size_t)(clsbase + mrow) * Hn + kseg * 8;
        #pragma unroll
        for (int kk = 0; kk < 32; ++kk) {
          v8h af = *(const v8h*)(ab + kk * 32);
          v8h bf = *(const v8h*)(hT + kk * 1024 + l * 16);
          acc = __builtin_amdgcn_mfma_f32_16x16x32_f16(af, bf, acc, 0, 0, 0);
        }
        v4f b4 = *(const v4f*)(fcb + clsbase + kseg * 4);
        v4f res = {acc[0] + b4[0], acc[1] + b4[1], acc[2] + b4[2], acc[3] + b4[3]};
        float* op = out + ((size_t)(b0f + mrow) * Tn + t) * Cn + clsbase + kseg * 4;
        *(v4f*)op = res;
      }
    }
  }
}

// ---------------------------------------------------------------------------
extern "C" void kernel_launch(void* const* d_in, const int* in_sizes, int n_in,
                              void* d_out, int out_size, void* d_ws, size_t ws_size,
                              hipStream_t stream) {
  const int*   x     = (const int*)  d_in[0];
  const float* embed = (const float*)d_in[1];
  const float* Wih   = (const float*)d_in[2];
  const float* Whh   = (const float*)d_in[3];
  const float* bih   = (const float*)d_in[4];
  const float* bhh   = (const float*)d_in[5];
  const float* fcW   = (const float*)d_in[6];
  const float* fcb   = (const float*)d_in[7];
  float* out = (float*)d_out;

  char* ws = (char*)d_ws;
  const size_t genBytes  = 128;                                        // NOT memset
  const size_t flagBytes = (size_t)Tn * 4 * 32 * 4;                    // 256 KB
  const size_t projBytes = (size_t)Cn * Gn * sizeof(float);            // 4 MB
  const size_t hsBytes   = (size_t)Tn * Bn * Hn * sizeof(_Float16);    // 64 MB
  const size_t fw16Bytes = (size_t)Cn * Hn * sizeof(_Float16);         // 512 KB
  const size_t hxLBytes  = 524288;                                     // 512 KB
  const size_t need = genBytes + flagBytes + projBytes + hsBytes + fw16Bytes + hxLBytes;
  if (ws_size < need) {
    hipMemsetAsync(d_out, 0, (size_t)out_size * sizeof(float), stream);
    return;
  }
  unsigned*  genc  = (unsigned*)ws;
  int*       flags = (int*)(ws + genBytes);
  float*     proj  = (float*)(ws + genBytes + flagBytes);
  _Float16*  hs16  = (_Float16*)(ws + genBytes + flagBytes + projBytes);
  _Float16*  fcW16 = (_Float16*)(ws + genBytes + flagBytes + projBytes + hsBytes);
  char*      hxL   = ws + genBytes + flagBytes + projBytes + hsBytes + fw16Bytes;

  // zero flags every call; gen cell and hxL are NOT cleared (gen-tags
  // make stale hxL lines unmatchable)
  hipMemsetAsync(ws + genBytes, 0, flagBytes, stream);

  // 0) generation bump + fcW fp16 convert
  gen_bump<<<1, 64, 0, stream>>>(genc);
  cvt_fcw<<<128, 256, 0, stream>>>(fcW, fcW16);

  // 1) proj[cls, 4H] = embed[cls,:] @ W_ih^T + b_ih + b_hh
  dim3 g1(Cn / 64, Gn / 64);   // (4, 64)
  gemm_tt<<<g1, 256, 0, stream>>>(embed, Wih, bih, bhh, proj, Cn, Gn, En);

  // 2) fused persistent LSTM + streaming FC
  lstm_fused<<<256, 512, 0, stream>>>(x, Whh, proj, hs16, flags, hxL, genc,
                                      fcW16, fcb, out);
}

// Round 15
// 2668.887 us; speedup vs baseline: 101.0805x; 101.0805x over previous
//
#include <hip/hip_runtime.h>
#include <math.h>

#define DEV_INLINE __device__ __forceinline__

static constexpr int Bn = 64;     // batch
static constexpr int Tn = 512;    // time
static constexpr int En = 512;    // embed
static constexpr int Hn = 1024;   // hidden
static constexpr int Cn = 256;    // classes
static constexpr int Gn = 4 * Hn; // 4096 gates

typedef float v4f __attribute__((ext_vector_type(4)));
typedef unsigned int v4u __attribute__((ext_vector_type(4)));
typedef _Float16 v8h __attribute__((ext_vector_type(8)));
typedef unsigned long long ull;

DEV_INLINE float sigmoidf_(float v) { return 1.f / (1.f + __expf(-v)); }

// ---------------------------------------------------------------------------
// fp32 tiled GEMM:  C[M,N] = A[M,K] * B[N,K]^T + bias1[n] (+bias2[n])
// ---------------------------------------------------------------------------
__global__ __launch_bounds__(256) void gemm_tt(
    const float* __restrict__ A, const float* __restrict__ Bm,
    const float* __restrict__ bias1, const float* __restrict__ bias2,
    float* __restrict__ Cm, int M, int N, int K)
{
  constexpr int KC = 32;
  __shared__ float As[KC][68];
  __shared__ float Bs[KC][68];
  const int tid = threadIdx.x;
  const int tx = tid & 15, ty = tid >> 4;
  const int m0 = blockIdx.x * 64, n0 = blockIdx.y * 64;

  float acc[4][4] = {};

  for (int k0 = 0; k0 < K; k0 += KC) {
    __syncthreads();
    #pragma unroll
    for (int j = 0; j < 2; ++j) {
      int f = tid + j * 256;
      int row = f >> 3;
      int c4 = f & 7;
      float4 va = *reinterpret_cast<const float4*>(&A[(size_t)(m0 + row) * K + k0 + c4 * 4]);
      As[c4 * 4 + 0][row] = va.x; As[c4 * 4 + 1][row] = va.y;
      As[c4 * 4 + 2][row] = va.z; As[c4 * 4 + 3][row] = va.w;
      float4 vb = *reinterpret_cast<const float4*>(&Bm[(size_t)(n0 + row) * K + k0 + c4 * 4]);
      Bs[c4 * 4 + 0][row] = vb.x; Bs[c4 * 4 + 1][row] = vb.y;
      Bs[c4 * 4 + 2][row] = vb.z; Bs[c4 * 4 + 3][row] = vb.w;
    }
    __syncthreads();
    #pragma unroll
    for (int k = 0; k < KC; ++k) {
      float4 a4 = *reinterpret_cast<const float4*>(&As[k][ty * 4]);
      float4 b4 = *reinterpret_cast<const float4*>(&Bs[k][tx * 4]);
      float ar[4] = {a4.x, a4.y, a4.z, a4.w};
      float br[4] = {b4.x, b4.y, b4.z, b4.w};
      #pragma unroll
      for (int i = 0; i < 4; ++i)
        #pragma unroll
        for (int j = 0; j < 4; ++j)
          acc[i][j] += ar[i] * br[j];
    }
  }

  #pragma unroll
  for (int j = 0; j < 4; ++j) {
    int n = n0 + tx * 4 + j;
    float bb = bias1[n];
    if (bias2) bb += bias2[n];
    #pragma unroll
    for (int i = 0; i < 4; ++i)
      Cm[(size_t)(m0 + ty * 4 + i) * N + n] = acc[i][j] + bb;
  }
}

// ---------------------------------------------------------------------------
__global__ __launch_bounds__(256) void cvt_fcw(
    const float* __restrict__ fcW, _Float16* __restrict__ fcW16)
{
  const int idx = (blockIdx.x * 256 + threadIdx.x) * 8;
  float4 f0 = *(const float4*)(fcW + idx);
  float4 f1 = *(const float4*)(fcW + idx + 4);
  v8h h8;
  h8[0] = (_Float16)f0.x; h8[1] = (_Float16)f0.y;
  h8[2] = (_Float16)f0.z; h8[3] = (_Float16)f0.w;
  h8[4] = (_Float16)f1.x; h8[5] = (_Float16)f1.y;
  h8[6] = (_Float16)f1.z; h8[7] = (_Float16)f1.w;
  *(v8h*)(fcW16 + idx) = h8;
}

// ---------------------------------------------------------------------------
// per-call generation bump (gen cell lives OUTSIDE the memset region)
// ---------------------------------------------------------------------------
__global__ void gen_bump(unsigned* g) {
  if (threadIdx.x == 0)
    __hip_atomic_fetch_add(g, 1u, __ATOMIC_RELAXED, __HIP_MEMORY_SCOPE_AGENT);
}

// ---------------------------------------------------------------------------
// Fused persistent kernel, 256 blocks x 512 threads.
//
// Blocks 0..127 — LSTM (bg=bid>>5, hg=bid&31): batches [bg*16,+16), h-cols
// [hg*32,+32). In-register gates (operand-swapped MFMA, R11-verified).
//
// Exchange (LSTM critical path): 16B tagged records ONLY.
//   Producer, end of step t (fire-and-forget, NO drain): 128 records
//   {8B h payload | 0 | tag<<16} -> hxL slot t&1, sc0 sc1 (device-visible;
//   liveness proven in R8). tag = ((gen&63)<<9 | t) + 1; gen bumped per
//   call -> stale lines can never match a current tag; 0xAA poison
//   (0xAAAA > max tag 0x8000) and memset-0 can never match; replay wrap
//   (gen mod 64) is benign: deterministic inputs => identical payloads.
//   Consumer, step t: poll ONE record (line's cg=7, 16B) until tag t-1
//   appears, then one validating sweep of the other 7 (stragglers retried).
//   16B store atomicity: tag visible => payload visible. Detect+stage
//   merge into ~1.5 fabric RTs; no drain, no flag in the chain.
//   Slot ping-pong safe: P writes slot t&1 at step t only after consuming
//   ALL t-1 records, which requires every block past its t-1 sweep.
//
// FC path (blocks 128..255) + its producer side: R12 VERBATIM — rows to
// hs16 (sc0 sc1) + wave-0 vmcnt drain + per-(t,bg) flag; FC polls flags
// with s_sleep(64) backoff. Off the LSTM critical path entirely.
// ---------------------------------------------------------------------------
__global__ __launch_bounds__(512, 2) void lstm_fused(
    const int* __restrict__ x,          // [B, T]
    const float* __restrict__ Whh,      // [4H, H] fp32
    const float* __restrict__ proj,     // [C, 4H] incl. both biases
    _Float16* __restrict__ hs16,        // [T, B, H] fp16 rows (FC input)
    int* __restrict__ flags,            // [Tn][4][32] dwords (128B lines)
    char* __restrict__ hxL,             // [2][4][32][128] x 16B tagged records
    unsigned* __restrict__ genc,        // generation cell (not memset)
    const _Float16* __restrict__ fcW16, // [256][1024] fp16
    const float* __restrict__ fcb,      // [256]
    float* __restrict__ out)            // [64][512][256] fp32
{
  __shared__ __align__(16) char hT[32768];   // staged h tile, fragment-linear
  __shared__ _Float16 hstage[16 * 40];       // stride 40: bank spread
  __shared__ unsigned genS;

  const int tid = threadIdx.x;
  const int bid = blockIdx.x;

  const int w = tid >> 6, l = tid & 63;
  const int mrow = l & 15;
  const int kseg = l >> 4;

  // staging source offset for the FC row path
  const int srcoff = (tid & 15) * 2048 + ((tid >> 4) & 3) * 16 + (tid >> 6) * 64;

  if (tid == 0)
    genS = __hip_atomic_load(genc, __ATOMIC_RELAXED, __HIP_MEMORY_SCOPE_AGENT);
  __syncthreads();
  const unsigned gen6 = (genS & 63u) << 9;

  if (bid < 128) {
    // =========================== LSTM path ===============================
    const int bg = bid >> 5, hg = bid & 31;
    const int b0 = bg * 16;

    // ---- W preload: A-row m=l&15 -> (gate=m&3, hcolLocal=w*4+(m>>2))
    v8h wv[32];
    {
      const float* wr = Whh
        + (size_t)((mrow & 3) * Hn + hg * 32 + w * 4 + (mrow >> 2)) * Hn
        + kseg * 8;
      #pragma unroll
      for (int kk = 0; kk < 32; ++kk) {
        const float* p = wr + kk * 32;
        float4 f0 = *(const float4*)p, f1 = *(const float4*)(p + 4);
        v8h h8;
        h8[0] = (_Float16)f0.x; h8[1] = (_Float16)f0.y;
        h8[2] = (_Float16)f0.z; h8[3] = (_Float16)f0.w;
        h8[4] = (_Float16)f1.x; h8[5] = (_Float16)f1.y;
        h8[6] = (_Float16)f1.z; h8[7] = (_Float16)f1.w;
        wv[kk] = h8;
      }
    }

    const int eb = mrow;            // elementwise: batch l&15
    const int ehc = w * 4 + kseg;   // hcol local
    const int* xp = x + (size_t)(b0 + eb) * Tn;
    float cst = 0.f;

    // consumer record line: producer p=tid>>4, batch=tid&15
    const int csrc  = (tid >> 4) * 2048 + (tid & 15) * 128;
    const int dbase = (tid >> 4) * 1024 + (tid & 15) * 16;

    for (int t = 0; t < Tn; ++t) {
      const int cls = xp[t];
      const float* pb = proj + (size_t)cls * Gn + hg * 32 + ehc;
      float p0 = pb[0], p1 = pb[Hn], p2 = pb[2 * Hn], p3 = pb[3 * Hn];

      v4f acc0 = {0.f, 0.f, 0.f, 0.f};
      v4f acc1 = {0.f, 0.f, 0.f, 0.f};

      if (t > 0) {
        // ---- detect on ONE record (cg=7), then validating sweep of 7
        const unsigned tagv = (gen6 | (unsigned)(t - 1)) + 1u;
        const char* pp = hxL + (size_t)((t - 1) & 1) * 262144
                       + bg * 65536 + csrc;
        v4u r7;
        do {
          asm volatile(
            "global_load_dwordx4 %0, %1, off offset:112 sc0 sc1\n\t"
            "s_waitcnt vmcnt(0)"
            : "=&v"(r7) : "v"(pp) : "memory");
        } while ((r7.w >> 16) != tagv);

        v4u r0, r1, r2, r3, r4, r5, r6;
        for (;;) {
          asm volatile(
            "global_load_dwordx4 %0, %7, off sc0 sc1\n\t"
            "global_load_dwordx4 %1, %7, off offset:16 sc0 sc1\n\t"
            "global_load_dwordx4 %2, %7, off offset:32 sc0 sc1\n\t"
            "global_load_dwordx4 %3, %7, off offset:48 sc0 sc1\n\t"
            "global_load_dwordx4 %4, %7, off offset:64 sc0 sc1\n\t"
            "global_load_dwordx4 %5, %7, off offset:80 sc0 sc1\n\t"
            "global_load_dwordx4 %6, %7, off offset:96 sc0 sc1\n\t"
            "s_waitcnt vmcnt(0)"
            : "=&v"(r0), "=&v"(r1), "=&v"(r2), "=&v"(r3),
              "=&v"(r4), "=&v"(r5), "=&v"(r6)
            : "v"(pp) : "memory");
          unsigned m = ((r0.w >> 16) ^ tagv) | ((r1.w >> 16) ^ tagv)
                     | ((r2.w >> 16) ^ tagv) | ((r3.w >> 16) ^ tagv)
                     | ((r4.w >> 16) ^ tagv) | ((r5.w >> 16) ^ tagv)
                     | ((r6.w >> 16) ^ tagv);
          if (m == 0u) break;      // stragglers only; usually one pass
        }
        // scatter payloads (8B each) into the fragment-linear A-tile
        v4u rr[8] = {r0, r1, r2, r3, r4, r5, r6, r7};
        #pragma unroll
        for (int i = 0; i < 8; ++i)
          *(ull*)(hT + dbase + (i >> 1) * 256 + (i & 1) * 8)
            = ((ull)rr[i].y << 32) | (ull)rr[i].x;
        __syncthreads();

        #pragma unroll
        for (int kk = 0; kk < 32; kk += 2) {
          v8h a0 = *(const v8h*)(hT + kk * 1024 + l * 16);
          v8h a1 = *(const v8h*)(hT + (kk + 1) * 1024 + l * 16);
          acc0 = __builtin_amdgcn_mfma_f32_16x16x32_f16(wv[kk], a0, acc0, 0, 0, 0);
          acc1 = __builtin_amdgcn_mfma_f32_16x16x32_f16(wv[kk + 1], a1, acc1, 0, 0, 0);
        }
      }

      // gates in-register: acc[r] = gate r of (eb, ehc)
      {
        float g0 = acc0[0] + acc1[0] + p0;
        float g1 = acc0[1] + acc1[1] + p1;
        float g2 = acc0[2] + acc1[2] + p2;
        float g3 = acc0[3] + acc1[3] + p3;
        float ig = sigmoidf_(g0), fg = sigmoidf_(g1);
        float gg = tanhf(g2),     og = sigmoidf_(g3);
        cst = fg * cst + ig * gg;
        hstage[eb * 40 + ehc] = (_Float16)(og * tanhf(cst));
      }
      __syncthreads();

      // ---- publish FAST records (fire-and-forget, LSTM consumers)
      if (tid < 128) {
        const int batch = tid >> 3, cg = tid & 7;
        ull d = *(const ull*)(hstage + batch * 40 + cg * 4);
        v4u val;
        val.x = (unsigned)d;
        val.y = (unsigned)(d >> 32);
        val.z = 0u;
        val.w = ((gen6 | (unsigned)t) + 1u) << 16;
        char* dst = hxL + (size_t)(t & 1) * 262144 + bg * 65536
                  + hg * 2048 + tid * 16;
        asm volatile("global_store_dwordx4 %0, %1, off sc0 sc1"
                     :: "v"(dst), "v"(val) : "memory");
      }
      // ---- publish rows + drain + flag (FC path only; R12-verified)
      if (tid < 64) {
        const int b = tid >> 2, part = tid & 3;
        v4f v = *(const v4f*)(hstage + b * 40 + part * 8);
        _Float16* dp = hs16 + ((size_t)t * Bn + b0 + b) * Hn + hg * 32 + part * 8;
        asm volatile(
          "global_store_dwordx4 %0, %1, off sc0 sc1\n\t"
          "s_waitcnt vmcnt(0)"
          :: "v"(dp), "v"(v) : "memory");
        if (tid == 0) {
          int one = 1;
          int* fq = flags + ((size_t)t * 4 + bg) * 32 + hg;
          asm volatile("global_store_dword %0, %1, off sc0 sc1"
                       :: "v"(fq), "v"(one) : "memory");
        }
      }
      __syncthreads();   // hstage/hT reuse next step
    }
  } else {
    // ============================ FC path (R12 verbatim) =================
    const int fid = bid - 128;

    for (int j = 0; j < 16; ++j) {
      const int unit = j * 128 + fid;          // 0..2047
      const int t = unit >> 2, bgf = unit & 3;
      const int b0f = bgf * 16;

      if (tid < 32) {
        const int* fp = flags + ((size_t)t * 4 + bgf) * 32 + tid;
        int v;
        for (;;) {
          asm volatile(
            "global_load_dword %0, %1, off sc0 sc1\n\t"
            "s_waitcnt vmcnt(0)"
            : "=v"(v) : "v"(fp) : "memory");
          if (v != 0) break;
          __builtin_amdgcn_s_sleep(64);
        }
      }
      __syncthreads();

      {
        const char* s0 = (const char*)(hs16 + ((size_t)t * Bn + b0f) * Hn)
                       + srcoff;
        v4f r0, r1, r2, r3;
        asm volatile(
          "global_load_dwordx4 %0, %4, off sc0 sc1\n\t"
          "global_load_dwordx4 %1, %5, off sc0 sc1\n\t"
          "global_load_dwordx4 %2, %6, off sc0 sc1\n\t"
          "global_load_dwordx4 %3, %7, off sc0 sc1\n\t"
          "s_waitcnt vmcnt(0)"
          : "=&v"(r0), "=&v"(r1), "=&v"(r2), "=&v"(r3)
          : "v"(s0), "v"(s0 + 512), "v"(s0 + 1024), "v"(s0 + 1536)
          : "memory");
        *(v4f*)(hT + tid * 16 +     0) = r0;
        *(v4f*)(hT + tid * 16 +  8192) = r1;
        *(v4f*)(hT + tid * 16 + 16384) = r2;
        *(v4f*)(hT + tid * 16 + 24576) = r3;
      }
      __syncthreads();

      #pragma unroll
      for (int nt = 0; nt < 2; ++nt) {
        const int clsbase = w * 32 + nt * 16;
        v4f acc = {0.f, 0.f, 0.f, 0.f};
        const _Float16* ab = fcW16 + (size_t)(clsbase + mrow) * Hn + kseg * 8;
        #pragma unroll
        for (int kk = 0; kk < 32; ++kk) {
          v8h af = *(const v8h*)(ab + kk * 32);
          v8h bf = *(const v8h*)(hT + kk * 1024 + l * 16);
          acc = __builtin_amdgcn_mfma_f32_16x16x32_f16(af, bf, acc, 0, 0, 0);
        }
        v4f b4 = *(const v4f*)(fcb + clsbase + kseg * 4);
        v4f res = {acc[0] + b4[0], acc[1] + b4[1], acc[2] + b4[2], acc[3] + b4[3]};
        float* op = out + ((size_t)(b0f + mrow) * Tn + t) * Cn + clsbase + kseg * 4;
        *(v4f*)op = res;
      }
    }
  }
}

// ---------------------------------------------------------------------------
extern "C" void kernel_launch(void* const* d_in, const int* in_sizes, int n_in,
                              void* d_out, int out_size, void* d_ws, size_t ws_size,
                              hipStream_t stream) {
  const int*   x     = (const int*)  d_in[0];
  const float* embed = (const float*)d_in[1];
  const float* Wih   = (const float*)d_in[2];
  const float* Whh   = (const float*)d_in[3];
  const float* bih   = (const float*)d_in[4];
  const float* bhh   = (const float*)d_in[5];
  const float* fcW   = (const float*)d_in[6];
  const float* fcb   = (const float*)d_in[7];
  float* out = (float*)d_out;

  char* ws = (char*)d_ws;
  const size_t genBytes  = 128;                                        // NOT memset
  const size_t flagBytes = (size_t)Tn * 4 * 32 * 4;                    // 256 KB
  const size_t projBytes = (size_t)Cn * Gn * sizeof(float);            // 4 MB
  const size_t hsBytes   = (size_t)Tn * Bn * Hn * sizeof(_Float16);    // 64 MB
  const size_t fw16Bytes = (size_t)Cn * Hn * sizeof(_Float16);         // 512 KB
  const size_t hxLBytes  = 524288;                                     // 512 KB
  const size_t need = genBytes + flagBytes + projBytes + hsBytes + fw16Bytes + hxLBytes;
  if (ws_size < need) {
    hipMemsetAsync(d_out, 0, (size_t)out_size * sizeof(float), stream);
    return;
  }
  unsigned*  genc  = (unsigned*)ws;
  int*       flags = (int*)(ws + genBytes);
  float*     proj  = (float*)(ws + genBytes + flagBytes);
  _Float16*  hs16  = (_Float16*)(ws + genBytes + flagBytes + projBytes);
  _Float16*  fcW16 = (_Float16*)(ws + genBytes + flagBytes + projBytes + hsBytes);
  char*      hxL   = ws + genBytes + flagBytes + projBytes + hsBytes + fw16Bytes;

  // zero flags every call; gen cell and hxL are NOT cleared (gen-tags make
  // stale hxL lines unmatchable; deterministic payloads make wrap benign)
  hipMemsetAsync(ws + genBytes, 0, flagBytes, stream);

  // 0) generation bump + fcW fp16 convert
  gen_bump<<<1, 64, 0, stream>>>(genc);
  cvt_fcw<<<128, 256, 0, stream>>>(fcW, fcW16);

  // 1) proj[cls, 4H] = embed[cls,:] @ W_ih^T + b_ih + b_hh
  dim3 g1(Cn / 64, Gn / 64);   // (4, 64)
  gemm_tt<<<g1, 256, 0, stream>>>(embed, Wih, bih, bhh, proj, Cn, Gn, En);

  // 2) fused persistent LSTM (records exchange) + streaming FC (flags)
  lstm_fused<<<256, 512, 0, stream>>>(x, Whh, proj, hs16, flags, hxL, genc,
                                      fcW16, fcb, out);
}

// Round 16
// 1971.789 us; speedup vs baseline: 136.8161x; 1.3535x over previous
//
#include <hip/hip_runtime.h>
#include <math.h>

#define DEV_INLINE __device__ __forceinline__

static constexpr int Bn = 64;     // batch
static constexpr int Tn = 512;    // time
static constexpr int En = 512;    // embed
static constexpr int Hn = 1024;   // hidden
static constexpr int Cn = 256;    // classes
static constexpr int Gn = 4 * Hn; // 4096 gates

typedef float v4f __attribute__((ext_vector_type(4)));
typedef _Float16 v8h __attribute__((ext_vector_type(8)));

DEV_INLINE float sigmoidf_(float v) { return 1.f / (1.f + __expf(-v)); }

// ---------------------------------------------------------------------------
// fp32 tiled GEMM:  C[M,N] = A[M,K] * B[N,K]^T + bias1[n] (+bias2[n])
// (used for proj = embed @ W_ih^T + b_ih + b_hh)
// ---------------------------------------------------------------------------
__global__ __launch_bounds__(256) void gemm_tt(
    const float* __restrict__ A, const float* __restrict__ Bm,
    const float* __restrict__ bias1, const float* __restrict__ bias2,
    float* __restrict__ Cm, int M, int N, int K)
{
  constexpr int KC = 32;
  __shared__ float As[KC][68];
  __shared__ float Bs[KC][68];
  const int tid = threadIdx.x;
  const int tx = tid & 15, ty = tid >> 4;
  const int m0 = blockIdx.x * 64, n0 = blockIdx.y * 64;

  float acc[4][4] = {};

  for (int k0 = 0; k0 < K; k0 += KC) {
    __syncthreads();
    #pragma unroll
    for (int j = 0; j < 2; ++j) {
      int f = tid + j * 256;
      int row = f >> 3;
      int c4 = f & 7;
      float4 va = *reinterpret_cast<const float4*>(&A[(size_t)(m0 + row) * K + k0 + c4 * 4]);
      As[c4 * 4 + 0][row] = va.x; As[c4 * 4 + 1][row] = va.y;
      As[c4 * 4 + 2][row] = va.z; As[c4 * 4 + 3][row] = va.w;
      float4 vb = *reinterpret_cast<const float4*>(&Bm[(size_t)(n0 + row) * K + k0 + c4 * 4]);
      Bs[c4 * 4 + 0][row] = vb.x; Bs[c4 * 4 + 1][row] = vb.y;
      Bs[c4 * 4 + 2][row] = vb.z; Bs[c4 * 4 + 3][row] = vb.w;
    }
    __syncthreads();
    #pragma unroll
    for (int k = 0; k < KC; ++k) {
      float4 a4 = *reinterpret_cast<const float4*>(&As[k][ty * 4]);
      float4 b4 = *reinterpret_cast<const float4*>(&Bs[k][tx * 4]);
      float ar[4] = {a4.x, a4.y, a4.z, a4.w};
      float br[4] = {b4.x, b4.y, b4.z, b4.w};
      #pragma unroll
      for (int i = 0; i < 4; ++i)
        #pragma unroll
        for (int j = 0; j < 4; ++j)
          acc[i][j] += ar[i] * br[j];
    }
  }

  #pragma unroll
  for (int j = 0; j < 4; ++j) {
    int n = n0 + tx * 4 + j;
    float bb = bias1[n];
    if (bias2) bb += bias2[n];
    #pragma unroll
    for (int i = 0; i < 4; ++i)
      Cm[(size_t)(m0 + ty * 4 + i) * N + n] = acc[i][j] + bb;
  }
}

// ---------------------------------------------------------------------------
// fcW fp32 -> fp16 convert (row-major [256][1024])
// ---------------------------------------------------------------------------
__global__ __launch_bounds__(256) void cvt_fcw(
    const float* __restrict__ fcW, _Float16* __restrict__ fcW16)
{
  const int idx = (blockIdx.x * 256 + threadIdx.x) * 8;   // 128 blocks cover 262144
  float4 f0 = *(const float4*)(fcW + idx);
  float4 f1 = *(const float4*)(fcW + idx + 4);
  v8h h8;
  h8[0] = (_Float16)f0.x; h8[1] = (_Float16)f0.y;
  h8[2] = (_Float16)f0.z; h8[3] = (_Float16)f0.w;
  h8[4] = (_Float16)f1.x; h8[5] = (_Float16)f1.y;
  h8[6] = (_Float16)f1.z; h8[7] = (_Float16)f1.w;
  *(v8h*)(fcW16 + idx) = h8;
}

// ---------------------------------------------------------------------------
// Fused persistent kernel, 256 blocks x 512 threads.  (R12-verified optimum)
//
// Blocks 0..127 — LSTM:
//   Block (bg=bid>>5, hg=bid&31): batches [bg*16,+16), h-cols [hg*32,+32).
//   In-register gates: acc = mfma(A=W_frag rows m=hcolLocal*4+gate, B=h_frag);
//   D (col=batch, row=4*kseg+r) gives each lane all 4 gates of its
//   (batch=l&15, hcol=w*4+kseg) — no LDS gate exchange.
//   TWO-PHASE split-K staging pipeline: h cols 0-511 are produced by hg
//   0-15, cols 512-1023 by hg 16-31.  pollA(flags 0-15) -> issue loads
//   r0,r1 -> pollB(flags 16-31, overlaps r0,r1 flight) -> issue r2,r3 ->
//   vmcnt(2) -> LDS-write A -> MFMA kk0-15 (r2,r3 in flight underneath)
//   -> vmcnt(0) -> LDS-write B (disjoint) -> MFMA kk16-31.
//   Producer side: wave-0 sc0 sc1 h stores, vmcnt drain, then flag dword;
//   per-(t,bg) 128B flag lines, memset'd each call.
//
// Blocks 128..255 — FC consumers (out[b][t][:] = hs16[t,b,:]@fcW^T+fcb):
//   unit (t,bg) = j*128+fid; poll full flag line with s_sleep(64) backoff,
//   stage, 2 class-tiles per wave via mfma(A=fcW16, B=h), v4f out stores.
// ---------------------------------------------------------------------------
__global__ __launch_bounds__(512, 2) void lstm_fused(
    const int* __restrict__ x,        // [B, T]
    const float* __restrict__ Whh,    // [4H, H] fp32
    const float* __restrict__ proj,   // [C, 4H] incl. both biases
    _Float16* __restrict__ hs16,      // [T, B, H] fp16 exchange buffer
    int* __restrict__ flags,          // [Tn][4][32] dwords (128B lines)
    const _Float16* __restrict__ fcW16, // [256][1024] fp16
    const float* __restrict__ fcb,    // [256]
    float* __restrict__ out)          // [64][512][256] fp32
{
  __shared__ __align__(16) char hT[32768];     // staged h tile, fragment-linear
  __shared__ _Float16 hstage[16 * 40];         // stride 40: 8-bank spread,
                                               // 80B rows (16B-aligned reads)

  const int tid = threadIdx.x;
  const int bid = blockIdx.x;

  const int w = tid >> 6, l = tid & 63;
  const int mrow = l & 15;                     // fragment row index
  const int kseg = l >> 4;                     // k-segment 0..3

  // staging source offset: dest hT + tid*16 + i*8192 is fragment-linear
  // [kk][kseg][batch-row]; swizzle lives in the global source address.
  const int srcoff = (tid & 15) * 2048 + ((tid >> 4) & 3) * 16 + (tid >> 6) * 64;

  if (bid < 128) {
    // =========================== LSTM path ===============================
    const int bg = bid >> 5, hg = bid & 31;
    const int b0 = bg * 16;

    // ---- W preload: lane's A-row m = l&15 -> (gate = m&3, hcolLocal =
    //      w*4 + (m>>2)); k-range kseg*8 + kk*32.
    v8h wv[32];
    {
      const float* wr = Whh
        + (size_t)((mrow & 3) * Hn + hg * 32 + w * 4 + (mrow >> 2)) * Hn
        + kseg * 8;
      #pragma unroll
      for (int kk = 0; kk < 32; ++kk) {
        const float* p = wr + kk * 32;
        float4 f0 = *(const float4*)p, f1 = *(const float4*)(p + 4);
        v8h h8;
        h8[0] = (_Float16)f0.x; h8[1] = (_Float16)f0.y;
        h8[2] = (_Float16)f0.z; h8[3] = (_Float16)f0.w;
        h8[4] = (_Float16)f1.x; h8[5] = (_Float16)f1.y;
        h8[6] = (_Float16)f1.z; h8[7] = (_Float16)f1.w;
        wv[kk] = h8;
      }
    }

    // elementwise identity (from D-fragment): batch l&15, hcol w*4+kseg
    const int eb = mrow;
    const int ehc = w * 4 + kseg;
    const int* xp = x + (size_t)(b0 + eb) * Tn;
    float cst = 0.f;

    for (int t = 0; t < Tn; ++t) {
      const int cls = xp[t];
      const float* pb = proj + (size_t)cls * Gn + hg * 32 + ehc;
      float p0 = pb[0], p1 = pb[Hn], p2 = pb[2 * Hn], p3 = pb[3 * Hn];

      v4f acc0 = {0.f, 0.f, 0.f, 0.f};
      v4f acc1 = {0.f, 0.f, 0.f, 0.f};

      if (t > 0) {
        const char* s0 = (const char*)(hs16 + ((size_t)(t - 1) * Bn + b0) * Hn)
                       + srcoff;
        // ---- phase A detect: cols 0-511 (producers hg 0-15)
        if (tid < 16) {
          const int* fp = flags + ((size_t)(t - 1) * 4 + bg) * 32 + tid;
          int v;
          do {
            asm volatile(
              "global_load_dword %0, %1, off sc0 sc1\n\t"
              "s_waitcnt vmcnt(0)"
              : "=v"(v) : "v"(fp) : "memory");
          } while (v == 0);
        }
        __syncthreads();
        // issue A loads, no wait
        v4f r0, r1, r2, r3;
        asm volatile(
          "global_load_dwordx4 %0, %2, off sc0 sc1\n\t"
          "global_load_dwordx4 %1, %3, off sc0 sc1"
          : "=&v"(r0), "=&v"(r1)
          : "v"(s0), "v"(s0 + 512) : "memory");
        // ---- phase B detect: cols 512-1023 (producers hg 16-31);
        //      overlaps the A loads' flight
        if (tid >= 16 && tid < 32) {
          const int* fp = flags + ((size_t)(t - 1) * 4 + bg) * 32 + tid;
          int v;
          do {
            asm volatile(
              "global_load_dword %0, %1, off sc0 sc1\n\t"
              "s_waitcnt vmcnt(0)"
              : "=v"(v) : "v"(fp) : "memory");
          } while (v == 0);
        }
        __syncthreads();
        // issue B loads, no wait
        asm volatile(
          "global_load_dwordx4 %0, %2, off sc0 sc1\n\t"
          "global_load_dwordx4 %1, %3, off sc0 sc1"
          : "=&v"(r2), "=&v"(r3)
          : "v"(s0 + 1024), "v"(s0 + 1536) : "memory");
        // wait A only (B stays in flight)
        asm volatile("s_waitcnt vmcnt(2)" ::: "memory");
        *(v4f*)(hT + tid * 16 +    0) = r0;
        *(v4f*)(hT + tid * 16 + 8192) = r1;
        __syncthreads();
        // MFMA over kk 0..15 while r2,r3 travel
        #pragma unroll
        for (int kk = 0; kk < 16; kk += 2) {
          v8h a0 = *(const v8h*)(hT + kk * 1024 + l * 16);
          v8h a1 = *(const v8h*)(hT + (kk + 1) * 1024 + l * 16);
          acc0 = __builtin_amdgcn_mfma_f32_16x16x32_f16(wv[kk], a0, acc0, 0, 0, 0);
          acc1 = __builtin_amdgcn_mfma_f32_16x16x32_f16(wv[kk + 1], a1, acc1, 0, 0, 0);
        }
        asm volatile("s_waitcnt vmcnt(0)" ::: "memory");
        *(v4f*)(hT + tid * 16 + 16384) = r2;   // disjoint from A region
        *(v4f*)(hT + tid * 16 + 24576) = r3;
        __syncthreads();
        #pragma unroll
        for (int kk = 16; kk < 32; kk += 2) {
          v8h a0 = *(const v8h*)(hT + kk * 1024 + l * 16);
          v8h a1 = *(const v8h*)(hT + (kk + 1) * 1024 + l * 16);
          acc0 = __builtin_amdgcn_mfma_f32_16x16x32_f16(wv[kk], a0, acc0, 0, 0, 0);
          acc1 = __builtin_amdgcn_mfma_f32_16x16x32_f16(wv[kk + 1], a1, acc1, 0, 0, 0);
        }
      }

      // gates in-register: acc[r] = gate r of (eb, ehc)
      {
        float g0 = acc0[0] + acc1[0] + p0;
        float g1 = acc0[1] + acc1[1] + p1;
        float g2 = acc0[2] + acc1[2] + p2;
        float g3 = acc0[3] + acc1[3] + p3;
        float ig = sigmoidf_(g0), fg = sigmoidf_(g1);
        float gg = tanhf(g2),     og = sigmoidf_(g3);
        cst = fg * cst + ig * gg;
        hstage[eb * 40 + ehc] = (_Float16)(og * tanhf(cst));
      }
      __syncthreads();

      if (tid < 64) {
        // 16B coherent stores; wave-0 vmcnt(0) drains before flag publish
        const int b = tid >> 2, part = tid & 3;
        v4f v = *(const v4f*)(hstage + b * 40 + part * 8);
        _Float16* dp = hs16 + ((size_t)t * Bn + b0 + b) * Hn + hg * 32 + part * 8;
        asm volatile(
          "global_store_dwordx4 %0, %1, off sc0 sc1\n\t"
          "s_waitcnt vmcnt(0)"
          :: "v"(dp), "v"(v) : "memory");
        if (tid == 0) {
          int one = 1;
          int* fq = flags + ((size_t)t * 4 + bg) * 32 + hg;
          asm volatile(
            "global_store_dword %0, %1, off sc0 sc1\n\t"
            "s_waitcnt vmcnt(0)"
            :: "v"(fq), "v"(one) : "memory");
        }
      }
      __syncthreads();   // hstage reuse next step
    }
  } else {
    // ============================ FC path ================================
    const int fid = bid - 128;

    for (int j = 0; j < 16; ++j) {
      const int unit = j * 128 + fid;          // 0..2047
      const int t = unit >> 2, bgf = unit & 3;
      const int b0f = bgf * 16;

      // wait for all 32 producers of (t, bgf); long sleep backoff
      if (tid < 32) {
        const int* fp = flags + ((size_t)t * 4 + bgf) * 32 + tid;
        int v;
        for (;;) {
          asm volatile(
            "global_load_dword %0, %1, off sc0 sc1\n\t"
            "s_waitcnt vmcnt(0)"
            : "=v"(v) : "v"(fp) : "memory");
          if (v != 0) break;
          __builtin_amdgcn_s_sleep(64);
        }
      }
      __syncthreads();   // also orders prev unit's hT reads before restage

      // stage hs16[t][b0f..+16][:] -> hT
      {
        const char* s0 = (const char*)(hs16 + ((size_t)t * Bn + b0f) * Hn)
                       + srcoff;
        v4f r0, r1, r2, r3;
        asm volatile(
          "global_load_dwordx4 %0, %4, off sc0 sc1\n\t"
          "global_load_dwordx4 %1, %5, off sc0 sc1\n\t"
          "global_load_dwordx4 %2, %6, off sc0 sc1\n\t"
          "global_load_dwordx4 %3, %7, off sc0 sc1\n\t"
          "s_waitcnt vmcnt(0)"
          : "=&v"(r0), "=&v"(r1), "=&v"(r2), "=&v"(r3)
          : "v"(s0), "v"(s0 + 512), "v"(s0 + 1024), "v"(s0 + 1536)
          : "memory");
        *(v4f*)(hT + tid * 16 +     0) = r0;
        *(v4f*)(hT + tid * 16 +  8192) = r1;
        *(v4f*)(hT + tid * 16 + 16384) = r2;
        *(v4f*)(hT + tid * 16 + 24576) = r3;
      }
      __syncthreads();

      // wave w covers classes [w*32, +32) as 2 tiles of 16
      #pragma unroll
      for (int nt = 0; nt < 2; ++nt) {
        const int clsbase = w * 32 + nt * 16;
        v4f acc = {0.f, 0.f, 0.f, 0.f};
        const _Float16* ab = fcW16 + (size_t)(clsbase + mrow) * Hn + kseg * 8;
        #pragma unroll
        for (int kk = 0; kk < 32; ++kk) {
          v8h af = *(const v8h*)(ab + kk * 32);
          v8h bf = *(const v8h*)(hT + kk * 1024 + l * 16);
          acc = __builtin_amdgcn_mfma_f32_16x16x32_f16(af, bf, acc, 0, 0, 0);
        }
        // D: row = 4*kseg + r = class-in-tile, col = l&15 = batch
        v4f b4 = *(const v4f*)(fcb + clsbase + kseg * 4);
        v4f res = {acc[0] + b4[0], acc[1] + b4[1], acc[2] + b4[2], acc[3] + b4[3]};
        float* op = out + ((size_t)(b0f + mrow) * Tn + t) * Cn + clsbase + kseg * 4;
        *(v4f*)op = res;
      }
    }
  }
}

// ---------------------------------------------------------------------------
extern "C" void kernel_launch(void* const* d_in, const int* in_sizes, int n_in,
                              void* d_out, int out_size, void* d_ws, size_t ws_size,
                              hipStream_t stream) {
  const int*   x     = (const int*)  d_in[0];
  const float* embed = (const float*)d_in[1];
  const float* Wih   = (const float*)d_in[2];
  const float* Whh   = (const float*)d_in[3];
  const float* bih   = (const float*)d_in[4];
  const float* bhh   = (const float*)d_in[5];
  const float* fcW   = (const float*)d_in[6];
  const float* fcb   = (const float*)d_in[7];
  float* out = (float*)d_out;

  char* ws = (char*)d_ws;
  const size_t flagBytes = (size_t)Tn * 4 * 32 * 4;                    // 256 KB
  const size_t projBytes = (size_t)Cn * Gn * sizeof(float);            // 4 MB
  const size_t hsBytes   = (size_t)Tn * Bn * Hn * sizeof(_Float16);    // 64 MB
  const size_t fw16Bytes = (size_t)Cn * Hn * sizeof(_Float16);         // 512 KB
  const size_t need = flagBytes + projBytes + hsBytes + fw16Bytes;
  if (ws_size < need) {
    hipMemsetAsync(d_out, 0, (size_t)out_size * sizeof(float), stream);
    return;
  }
  float*     proj  = (float*)(ws + flagBytes);
  _Float16*  hs16  = (_Float16*)(ws + flagBytes + projBytes);
  _Float16*  fcW16 = (_Float16*)(ws + flagBytes + projBytes + hsBytes);

  // zero flags every call (graph-capture-safe async memset)
  hipMemsetAsync(d_ws, 0, flagBytes, stream);

  // 0) fcW -> fp16
  cvt_fcw<<<128, 256, 0, stream>>>(fcW, fcW16);

  // 1) proj[cls, 4H] = embed[cls,:] @ W_ih^T + b_ih + b_hh
  dim3 g1(Cn / 64, Gn / 64);   // (4, 64)
  gemm_tt<<<g1, 256, 0, stream>>>(embed, Wih, bih, bhh, proj, Cn, Gn, En);

  // 2) fused persistent LSTM (blocks 0-127) + streaming FC (blocks 128-255)
  lstm_fused<<<256, 512, 0, stream>>>(x, Whh, proj, hs16, (int*)d_ws,
                                      fcW16, fcb, out);
}